// Round 1
// baseline (99.900 us; speedup 1.0000x reference)
//
#include <hip/hip_runtime.h>

// out[b,t,h,f] = in[b,t,f] * w[f,h] + bias[f,h]
// B=32 T=512 F=64 H=64. Output (B,T,H,F) fp32 = 256 MiB -> HBM-write-bound.

constexpr int Fdim = 64;
constexpr int Hdim = 64;
constexpr int ROWS_PER_BLOCK = 8;   // rows (b,t) per block
constexpr int BLOCK = 256;

__global__ __launch_bounds__(BLOCK) void embed_mad_kernel(
    const float* __restrict__ in,    // [B*T, F]
    const float* __restrict__ w,     // [F, H]
    const float* __restrict__ bias,  // [F, H]
    float* __restrict__ out)         // [B*T, H, F]
{
    // Stage weight/bias transposed to [h][f] so the hot loop reads are
    // contiguous float4 per (h, f4) and the FMA matches the output layout.
    __shared__ float wT[Hdim * Fdim];
    __shared__ float bT[Hdim * Fdim];

    for (int idx = threadIdx.x; idx < Fdim * Hdim; idx += BLOCK) {
        // w layout: idx = f*H + h  (coalesced read)
        int f = idx >> 6;
        int h = idx & 63;
        wT[h * Fdim + f] = w[idx];
        bT[h * Fdim + f] = bias[idx];
    }
    __syncthreads();

    const int tid = threadIdx.x;
    const int f4 = (tid & 15) * 4;   // which float4 along F
    const int hq = tid >> 4;         // 0..15: h sub-index

    const int row0 = blockIdx.x * ROWS_PER_BLOCK;

    for (int r = row0; r < row0 + ROWS_PER_BLOCK; ++r) {
        // 4 consecutive input features for this thread, reused across all h.
        const float4 iv = *reinterpret_cast<const float4*>(&in[r * Fdim + f4]);
        float* outr = out + (size_t)r * (Hdim * Fdim);

#pragma unroll
        for (int hb = 0; hb < 4; ++hb) {
            const int h = hb * 16 + hq;
            const float4 wv = *reinterpret_cast<const float4*>(&wT[h * Fdim + f4]);
            const float4 bv = *reinterpret_cast<const float4*>(&bT[h * Fdim + f4]);
            float4 ov;
            ov.x = fmaf(iv.x, wv.x, bv.x);
            ov.y = fmaf(iv.y, wv.y, bv.y);
            ov.z = fmaf(iv.z, wv.z, bv.z);
            ov.w = fmaf(iv.w, wv.w, bv.w);
            // Block-contiguous: 256 threads x float4 = 4 KiB per hb step.
            *reinterpret_cast<float4*>(&outr[h * Fdim + f4]) = ov;
        }
    }
}

extern "C" void kernel_launch(void* const* d_in, const int* in_sizes, int n_in,
                              void* d_out, int out_size, void* d_ws, size_t ws_size,
                              hipStream_t stream) {
    const float* in   = (const float*)d_in[0];  // (B,T,F) fp32
    const float* w    = (const float*)d_in[1];  // (F,H) fp32
    const float* bias = (const float*)d_in[2];  // (F,H) fp32
    float* out = (float*)d_out;                 // (B,T,H,F) fp32

    const int rows = in_sizes[0] / Fdim;        // B*T = 16384
    const int grid = rows / ROWS_PER_BLOCK;     // 2048

    embed_mad_kernel<<<grid, BLOCK, 0, stream>>>(in, w, bias, out);
}

// Round 3
// 60.427 us; speedup vs baseline: 1.6532x; 1.6532x over previous
//
#include <hip/hip_runtime.h>

// out[b,t,h,f] = in[b,t,f] * w[f,h] + bias[f,h]
// B=32 T=512 F=64 H=64. Output (B,T,H,F) fp32 = 256 MiB -> HBM-write-bound.
// Strategy: per-thread register cache of the 8 (w,b) float4 fragments;
// hot loop = fma + nontemporal global_store_dwordx4 only.

constexpr int Fdim = 64;
constexpr int Hdim = 64;
constexpr int ROWS = 8;     // rows (b,t) per block
constexpr int BLOCK = 256;

typedef float floatx4 __attribute__((ext_vector_type(4)));  // clang vector: nt-store OK

__global__ __launch_bounds__(BLOCK) void embed_mad_kernel(
    const float* __restrict__ in,    // [B*T, F]
    const float* __restrict__ w,     // [F, H]
    const float* __restrict__ bias,  // [F, H]
    float* __restrict__ out)         // [B*T, H, F]
{
    // One 16 KiB buffer, staged twice (w then bias) -> 8 blocks/CU resident.
    __shared__ float s[Hdim * Fdim];

    const int tid = threadIdx.x;
    const int f4 = (tid & 15) * 4;   // float4 position along F
    const int hq = tid >> 4;         // 0..15: h sub-index

    // --- stage w transposed: s[h*F + f] = w[f*H + h] ---
    for (int idx = tid; idx < Fdim * Hdim; idx += BLOCK) {
        int f = idx >> 6;
        int h = idx & 63;
        s[h * Fdim + f] = w[idx];
    }
    __syncthreads();
    floatx4 wr[4];
#pragma unroll
    for (int hb = 0; hb < 4; ++hb)
        wr[hb] = *reinterpret_cast<const floatx4*>(&s[(hb * 16 + hq) * Fdim + f4]);
    __syncthreads();

    // --- stage bias transposed ---
    for (int idx = tid; idx < Fdim * Hdim; idx += BLOCK) {
        int f = idx >> 6;
        int h = idx & 63;
        s[h * Fdim + f] = bias[idx];
    }
    __syncthreads();
    floatx4 br[4];
#pragma unroll
    for (int hb = 0; hb < 4; ++hb)
        br[hb] = *reinterpret_cast<const floatx4*>(&s[(hb * 16 + hq) * Fdim + f4]);

    // --- preload all 8 input-row fragments (latency fully overlapped) ---
    const int row0 = blockIdx.x * ROWS;
    const float* inp = in + (size_t)row0 * Fdim + f4;
    floatx4 iv[ROWS];
#pragma unroll
    for (int r = 0; r < ROWS; ++r)
        iv[r] = *reinterpret_cast<const floatx4*>(inp + r * Fdim);

    // --- hot loop: pure FMA + nontemporal coalesced stores ---
    float* outp = out + (size_t)row0 * (Hdim * Fdim);
#pragma unroll
    for (int r = 0; r < ROWS; ++r) {
        float* outr = outp + r * (Hdim * Fdim);
#pragma unroll
        for (int hb = 0; hb < 4; ++hb) {
            const int h = hb * 16 + hq;
            floatx4 ov;
            ov.x = fmaf(iv[r].x, wr[hb].x, br[hb].x);
            ov.y = fmaf(iv[r].y, wr[hb].y, br[hb].y);
            ov.z = fmaf(iv[r].z, wr[hb].z, br[hb].z);
            ov.w = fmaf(iv[r].w, wr[hb].w, br[hb].w);
            // Wave-contiguous 1 KiB per store; output never re-read -> nt.
            __builtin_nontemporal_store(ov, reinterpret_cast<floatx4*>(&outr[h * Fdim + f4]));
        }
    }
}

extern "C" void kernel_launch(void* const* d_in, const int* in_sizes, int n_in,
                              void* d_out, int out_size, void* d_ws, size_t ws_size,
                              hipStream_t stream) {
    const float* in   = (const float*)d_in[0];  // (B,T,F) fp32
    const float* w    = (const float*)d_in[1];  // (F,H) fp32
    const float* bias = (const float*)d_in[2];  // (F,H) fp32
    float* out = (float*)d_out;                 // (B,T,H,F) fp32

    const int rows = in_sizes[0] / Fdim;        // B*T = 16384
    const int grid = rows / ROWS;               // 2048

    embed_mad_kernel<<<grid, BLOCK, 0, stream>>>(in, w, bias, out);
}

// Round 4
// 59.350 us; speedup vs baseline: 1.6832x; 1.0181x over previous
//
#include <hip/hip_runtime.h>

// out[b,t,h,f] = in[b,t,f] * w[f,h] + bias[f,h]
// B=32 T=512 F=64 H=64. Output (B,T,H,F) fp32 = 256 MiB -> HBM-write-bound.
// Register-cached w/b fragments; hot loop = fma + PLAIN global_store_dwordx4
// (round-3 post-mortem: nt stores bypass L2 write-aggregation -> 4.5 TB/s;
// plain write-back stores should aggregate to full-line HBM writes like
// fillBufferAligned's ~7 TB/s).

constexpr int Fdim = 64;
constexpr int Hdim = 64;
constexpr int ROWS = 8;     // rows (b,t) per block
constexpr int BLOCK = 256;

typedef float floatx4 __attribute__((ext_vector_type(4)));

__global__ __launch_bounds__(BLOCK) void embed_mad_kernel(
    const float* __restrict__ in,    // [B*T, F]
    const float* __restrict__ w,     // [F, H]
    const float* __restrict__ bias,  // [F, H]
    float* __restrict__ out)         // [B*T, H, F]
{
    // One 16 KiB buffer, staged twice (w then bias) -> 8 blocks/CU resident.
    __shared__ float s[Hdim * Fdim];

    const int tid = threadIdx.x;
    const int f4 = (tid & 15) * 4;   // float4 position along F
    const int hq = tid >> 4;         // 0..15: h sub-index

    // --- stage w transposed: s[h*F + f] = w[f*H + h] ---
    for (int idx = tid; idx < Fdim * Hdim; idx += BLOCK) {
        int f = idx >> 6;
        int h = idx & 63;
        s[h * Fdim + f] = w[idx];
    }
    __syncthreads();
    floatx4 wr[4];
#pragma unroll
    for (int hb = 0; hb < 4; ++hb)
        wr[hb] = *reinterpret_cast<const floatx4*>(&s[(hb * 16 + hq) * Fdim + f4]);
    __syncthreads();

    // --- stage bias transposed ---
    for (int idx = tid; idx < Fdim * Hdim; idx += BLOCK) {
        int f = idx >> 6;
        int h = idx & 63;
        s[h * Fdim + f] = bias[idx];
    }
    __syncthreads();
    floatx4 br[4];
#pragma unroll
    for (int hb = 0; hb < 4; ++hb)
        br[hb] = *reinterpret_cast<const floatx4*>(&s[(hb * 16 + hq) * Fdim + f4]);

    // --- preload all 8 input-row fragments (latency fully overlapped) ---
    const int row0 = blockIdx.x * ROWS;
    const float* inp = in + (size_t)row0 * Fdim + f4;
    floatx4 iv[ROWS];
#pragma unroll
    for (int r = 0; r < ROWS; ++r)
        iv[r] = *reinterpret_cast<const floatx4*>(inp + r * Fdim);

    // --- hot loop: pure FMA + coalesced plain stores (L2 write-back) ---
    float* outp = out + (size_t)row0 * (Hdim * Fdim);
#pragma unroll
    for (int r = 0; r < ROWS; ++r) {
        float* outr = outp + r * (Hdim * Fdim);
#pragma unroll
        for (int hb = 0; hb < 4; ++hb) {
            const int h = hb * 16 + hq;
            floatx4 ov;
            ov.x = fmaf(iv[r].x, wr[hb].x, br[hb].x);
            ov.y = fmaf(iv[r].y, wr[hb].y, br[hb].y);
            ov.z = fmaf(iv[r].z, wr[hb].z, br[hb].z);
            ov.w = fmaf(iv[r].w, wr[hb].w, br[hb].w);
            // Wave-contiguous 1 KiB per store instruction.
            *reinterpret_cast<floatx4*>(&outr[h * Fdim + f4]) = ov;
        }
    }
}

extern "C" void kernel_launch(void* const* d_in, const int* in_sizes, int n_in,
                              void* d_out, int out_size, void* d_ws, size_t ws_size,
                              hipStream_t stream) {
    const float* in   = (const float*)d_in[0];  // (B,T,F) fp32
    const float* w    = (const float*)d_in[1];  // (F,H) fp32
    const float* bias = (const float*)d_in[2];  // (F,H) fp32
    float* out = (float*)d_out;                 // (B,T,H,F) fp32

    const int rows = in_sizes[0] / Fdim;        // B*T = 16384
    const int grid = rows / ROWS;               // 2048

    embed_mad_kernel<<<grid, BLOCK, 0, stream>>>(in, w, bias, out);
}

// Round 5
// 59.092 us; speedup vs baseline: 1.6906x; 1.0044x over previous
//
#include <hip/hip_runtime.h>

// out[b,t,h,f] = in[b,t,f] * w[f,h] + bias[f,h]
// B=32 T=512 F=64 H=64. Output (B,T,H,F) fp32 = 256 MiB -> HBM-write-bound.
//
// Round-5 structure: flat grid-stride sweep (fillBuffer-shaped single write
// front). Stride = GRID*BLOCK*4 floats = 1Mi floats = exactly 256 output rows,
// so each thread's (h, f4) is INVARIANT across iterations: w/b fragments live
// in one float4 register pair each; hot loop = broadcast input load (cache-hit)
// + 4 FMA + one wave-contiguous 1 KiB store. No LDS/barriers in hot loop.

constexpr int Fdim = 64;
constexpr int Hdim = 64;
constexpr int BLOCK = 256;
constexpr int GRID = 1024;   // 4 blocks/CU; front = 4 MiB; 64 iterations

typedef float floatx4 __attribute__((ext_vector_type(4)));

__global__ __launch_bounds__(BLOCK) void embed_mad_kernel(
    const float* __restrict__ in,    // [B*T, F]
    const float* __restrict__ w,     // [F, H]
    const float* __restrict__ bias,  // [F, H]
    float* __restrict__ out,         // [B*T, H, F]
    int iters)
{
    // Prologue: LDS-transpose w then bias through one 16 KiB buffer so each
    // thread picks up its single (h, f4) fragment with coalesced global reads.
    __shared__ float s[Hdim * Fdim];
    const int tid = threadIdx.x;

    for (int idx = tid; idx < Fdim * Hdim; idx += BLOCK) {
        int f = idx >> 6;
        int h = idx & 63;
        s[h * Fdim + f] = w[idx];
    }
    __syncthreads();

    const int gtid = blockIdx.x * BLOCK + tid;
    const int o0 = gtid * 4;            // flat float index of this thread's float4
    const int f4 = o0 & 63;             // feature offset (invariant)
    const int h  = (o0 >> 6) & 63;      // hidden index  (invariant)

    floatx4 wv = *reinterpret_cast<const floatx4*>(&s[h * Fdim + f4]);
    __syncthreads();

    for (int idx = tid; idx < Fdim * Hdim; idx += BLOCK) {
        int f = idx >> 6;
        int hh = idx & 63;
        s[hh * Fdim + f] = bias[idx];
    }
    __syncthreads();
    floatx4 bv = *reinterpret_cast<const floatx4*>(&s[h * Fdim + f4]);

    // Hot loop: single sweeping front. step is a multiple of the 4096-float
    // row, so only the row index advances (+256 rows/iter).
    constexpr int STEP = GRID * BLOCK * 4;            // 1,048,576 floats
    constexpr int ROWSTEP = STEP / (Hdim * Fdim);     // 256 rows
    const float* ip = in + (size_t)(o0 >> 12) * Fdim + f4;
    float* op = out + o0;

#pragma unroll 4
    for (int it = 0; it < iters; ++it) {
        floatx4 iv = *reinterpret_cast<const floatx4*>(ip);
        floatx4 ov;
        ov.x = fmaf(iv.x, wv.x, bv.x);
        ov.y = fmaf(iv.y, wv.y, bv.y);
        ov.z = fmaf(iv.z, wv.z, bv.z);
        ov.w = fmaf(iv.w, wv.w, bv.w);
        *reinterpret_cast<floatx4*>(op) = ov;
        ip += ROWSTEP * Fdim;
        op += STEP;
    }
}

extern "C" void kernel_launch(void* const* d_in, const int* in_sizes, int n_in,
                              void* d_out, int out_size, void* d_ws, size_t ws_size,
                              hipStream_t stream) {
    const float* in   = (const float*)d_in[0];  // (B,T,F) fp32
    const float* w    = (const float*)d_in[1];  // (F,H) fp32
    const float* bias = (const float*)d_in[2];  // (F,H) fp32
    float* out = (float*)d_out;                 // (B,T,H,F) fp32

    const int iters = out_size / (GRID * BLOCK * 4);   // 64 for B*T=16384

    embed_mad_kernel<<<GRID, BLOCK, 0, stream>>>(in, w, bias, out, iters);
}